// Round 3
// baseline (630.735 us; speedup 1.0000x reference)
//
#include <hip/hip_runtime.h>
#include <stdint.h>

// ---------------------------------------------------------------------------
// out[n_tok, out_f] = input @ (w_scale * round(weight))^T + b_scale*round(bias)
// M=8192, N=4096, K=4096, fp32 in/out.
//
// R7: R4/R5/R6 (three different phase/barrier structures) all tied at
// 310-318us, MfmaUtil ~38, SQ_LDS_BANK_CONFLICT = 2.517e7 (= +4.0 cy per
// ds_read_b128, deterministic). Schedule is NOT the constraint; the shared
// LDS layout is: row stride 128B == 0 mod 32 banks, so bank group depends
// only on k-chunk slot; lanes {x,x+8,x+16,x+24} share slot -> structural
// multi-way conflict on every fragment read. LDS pipe ~65% busy + stalls.
//
// Fix (single variable vs R6): FRAGMENT-MAJOR LDS. Each 32x32x16 MFMA
// fragment = one contiguous 1024B lane-ordered block:
//   - ds_read_b128 = uniform_base + lane*16 -> stride-1, conflict-free by
//     construction (m136). All read offsets are compile-time immediates.
//   - gload_lds writes wave_base + lane*16, so staging one fragment per
//     gload_lds with per-lane global addr
//     A[(bm+mb*32+(lane&31))*K + kt + ks*16 + (lane>>5)*8]
//     makes the write mapping == MFMA operand mapping. No XOR anywhere.
//   - HBM: each 128B row-line now served as 4x 32B requests (same bytes,
//     L2 absorbs granularity).
// Stage slots keep R6's counted-vmcnt discipline: p0 = 4 B-frags (nb=wave,
// ks0..3), p1 = 2 A-frags mb in {0,1,4,5}, p3 = 2 A-frags mb in {2,3,6,7}
// (deadline D2/D3, gated by end-p1 vmcnt(6)). Last-tile fix: when no stages
// are issued (t+1==NT), end-p1 drains vmcnt(0) -- R6's vmcnt(6) there did
// not actually force the 2 outstanding p3 stages (latent race).
// ---------------------------------------------------------------------------

using bf16x8   = __attribute__((ext_vector_type(8))) __bf16;
using floatx16 = __attribute__((ext_vector_type(16))) float;
using us8      = __attribute__((ext_vector_type(8))) unsigned short;
using us4      = __attribute__((ext_vector_type(4))) unsigned short;

__device__ __forceinline__ unsigned short f2bf_rne(float x) {
    unsigned int u = __float_as_uint(x);
    return (unsigned short)((u + 0x7fffu + ((u >> 16) & 1u)) >> 16);
}

__device__ __forceinline__ void stage16(const unsigned short* g, unsigned short* l) {
    __builtin_amdgcn_global_load_lds(
        (__attribute__((address_space(1))) void*)g,
        (__attribute__((address_space(3))) void*)l,
        16, 0, 0);
}

// ---------------------------------------------------------------------------
// Fused fp32->bf16 conversion: A (identity) then B (rintf). Coalesced 16B/lane.
// ---------------------------------------------------------------------------
__global__ __launch_bounds__(256) void cvt_both(
    const float* __restrict__ inA, unsigned short* __restrict__ outA, long long nA4,
    const float* __restrict__ inB, unsigned short* __restrict__ outB, long long nB4) {
    const long long i = (long long)blockIdx.x * 256 + threadIdx.x;
    if (i < nA4) {
        float4 v = ((const float4*)inA)[i];
        us4 o = { f2bf_rne(v.x), f2bf_rne(v.y), f2bf_rne(v.z), f2bf_rne(v.w) };
        ((us4*)outA)[i] = o;
    } else {
        const long long j = i - nA4;
        if (j < nB4) {
            float4 v = ((const float4*)inB)[j];
            us4 o = { f2bf_rne(rintf(v.x)), f2bf_rne(rintf(v.y)),
                      f2bf_rne(rintf(v.z)), f2bf_rne(rintf(v.w)) };
            ((us4*)outB)[j] = o;
        }
    }
}

// ---------------------------------------------------------------------------
// 256x256 phase-paired bf16 GEMM, B^T layout, fragment-major LDS.
// Block=512 (8 waves, 2Mx4N). Wave -> 128x64 output; 4x2 grid of 32x32x16
// MFMA accumulators. LDS per matrix per buffer: 32 frag-blocks x 1024B
// (A: (mb,ks), B: (nb,ks), block idx = mb*4+ks) = 32 KiB; x2 matrices
// x2 buffers = 128 KiB.
// ---------------------------------------------------------------------------
__global__ __launch_bounds__(512) void gemm256_fm(
    const unsigned short* __restrict__ A,   // [M][K] bf16
    const unsigned short* __restrict__ B,   // [N][K] bf16 (exact ints)
    const float* __restrict__ bias,
    const float* __restrict__ wscale_p,
    const float* __restrict__ bscale_p,
    float* __restrict__ C,                  // [M][N] fp32
    int M, int N, int K) {
    constexpr int BK   = 64;
    constexpr int TILE = 16384;                 // shorts per matrix per buffer
    __shared__ unsigned short ldsA[2 * TILE];   // 64 KiB
    __shared__ unsigned short ldsB[2 * TILE];   // 64 KiB

    const int tid  = threadIdx.x;
    const int wave = tid >> 6;
    const int lane = tid & 63;

    // bijective XCD swizzle (host guarantees gridDim.x % 8 == 0)
    const int nbx = N >> 8;
    int wg;
    {
        const int cpx = (int)gridDim.x >> 3;
        wg = ((int)blockIdx.x & 7) * cpx + ((int)blockIdx.x >> 3);
    }
    const int bm = (wg / nbx) << 8;
    const int bn = (wg % nbx) << 8;

    const int wr    = wave >> 2;          // 0/1   -> A rows wr*128
    const int wc    = wave & 3;           // 0..3  -> B rows wc*64
    const int col   = lane & 31;
    const int khalf = lane >> 5;

    // ---- staging assignment (per wave):
    // p0: B frags (nb=wave, ks=0..3); p1: A frags (mb1, kb..kb+1);
    // p3: A frags (mb3, kb..kb+1).  mb1 in {0,1,4,5}, mb3 = mb1+2.
    const int q   = wave >> 1;
    const int mb1 = (q & 1) + ((q >> 1) << 2);  // 0,1,4,5
    const int mb3 = mb1 + 2;                    // 2,3,6,7
    const int kb  = (wave & 1) << 1;            // 0 or 2

    // per-lane global bases: lane covers (row = base+col, k-half = khalf)
    const unsigned short* gAl = A + (size_t)(bm + col) * K + (khalf << 3);
    const unsigned short* gBl = B + (size_t)(bn + col) * K + (khalf << 3);

    const int lane16 = lane << 3;               // shorts (= lane*16 bytes)

    const float wsc = wscale_p[0];
    const float bsc = bscale_p[0];
    float badd[2];
#pragma unroll
    for (int ni = 0; ni < 2; ++ni)
        badd[ni] = bsc * rintf(bias[bn + wc * 64 + ni * 32 + col]);

    const int NT = K >> 6;

    // frag-block short-offset helpers (all compile-time per unrolled site)
#define ABLK(buf, mb, ks) ((buf) * TILE + (((mb) * 4 + (ks)) << 9))
#define BBLK(buf, nb, ks) ((buf) * TILE + (((nb) * 4 + (ks)) << 9))
#define ST_A(buf, mb, ks, kt) \
    stage16(gAl + (size_t)((mb) * 32) * K + (kt) + (ks) * 16, &ldsA[ABLK(buf, mb, ks)])
#define ST_B(buf, nb, ks, kt) \
    stage16(gBl + (size_t)((nb) * 32) * K + (kt) + (ks) * 16, &ldsB[BBLK(buf, nb, ks)])
#define RD_A(buf, mb, ks) \
    __builtin_bit_cast(bf16x8, *(const us8*)&ldsA[ABLK(buf, mb, ks) + lane16])
#define RD_B(buf, nb, ks) \
    __builtin_bit_cast(bf16x8, *(const us8*)&ldsB[BBLK(buf, nb, ks) + lane16])

    // ---- prologue: stage tile 0 -> buf0. 6 D01-class first, then 2 D23.
#pragma unroll
    for (int i = 0; i < 4; ++i) ST_B(0, wave, i, 0);
    ST_A(0, mb1, kb, 0);
    ST_A(0, mb1, kb + 1, 0);
    ST_A(0, mb3, kb, 0);
    ST_A(0, mb3, kb + 1, 0);
    asm volatile("s_waitcnt vmcnt(2)" ::: "memory");   // D01 landed
    __builtin_amdgcn_s_barrier();
    __builtin_amdgcn_sched_barrier(0);

    floatx16 acc[4][2] = {};

#define PH_BAR_LGKM()                                        \
    __builtin_amdgcn_s_barrier();                            \
    asm volatile("s_waitcnt lgkmcnt(0)" ::: "memory");       \
    __builtin_amdgcn_sched_barrier(0);

#define PH_MFMA(MIB, KSB)                                                     \
    __builtin_amdgcn_s_setprio(1);                                            \
    _Pragma("unroll") for (int k2 = 0; k2 < 2; ++k2)                          \
        _Pragma("unroll") for (int m2 = 0; m2 < 2; ++m2)                      \
            _Pragma("unroll") for (int ni = 0; ni < 2; ++ni)                  \
                acc[(MIB) + m2][ni] = __builtin_amdgcn_mfma_f32_32x32x16_bf16(\
                    Af[m2][k2], Bf[ni][(KSB) + k2], acc[(MIB) + m2][ni],      \
                    0, 0, 0);                                                 \
    __builtin_amdgcn_s_setprio(0);                                            \
    __builtin_amdgcn_sched_barrier(0);

    for (int t = 0; t < NT; ++t) {
        const int rb_ = t & 1;
        const int sb_ = (t + 1) & 1;
        const int kt1 = (t + 1) * BK;
        const bool st = (t + 1 < NT);

        bf16x8 Af[2][2];
        bf16x8 Bf[2][4];

        // ---- phase 0: A(wr*4+{0,1}, ks{0,1}), B(wc*2+{0,1}, ks{0,1});
        //      stage 4 B-frags of tile t+1
#pragma unroll
        for (int m2 = 0; m2 < 2; ++m2)
#pragma unroll
            for (int k2 = 0; k2 < 2; ++k2) Af[m2][k2] = RD_A(rb_, wr * 4 + m2, k2);
#pragma unroll
        for (int ni = 0; ni < 2; ++ni)
#pragma unroll
            for (int k2 = 0; k2 < 2; ++k2) Bf[ni][k2] = RD_B(rb_, wc * 2 + ni, k2);
        if (st) {
#pragma unroll
            for (int i = 0; i < 4; ++i) ST_B(sb_, wave, i, kt1);
        }
        PH_BAR_LGKM()
        PH_MFMA(0, 0)
        __builtin_amdgcn_s_barrier();
        __builtin_amdgcn_sched_barrier(0);

        // ---- phase 1: A(wr*4+{0,1}, ks{2,3}), B(.., ks{2,3}); stage A mb1 pair
#pragma unroll
        for (int m2 = 0; m2 < 2; ++m2)
#pragma unroll
            for (int k2 = 0; k2 < 2; ++k2) Af[m2][k2] = RD_A(rb_, wr * 4 + m2, 2 + k2);
#pragma unroll
        for (int ni = 0; ni < 2; ++ni)
#pragma unroll
            for (int k2 = 0; k2 < 2; ++k2) Bf[ni][2 + k2] = RD_B(rb_, wc * 2 + ni, 2 + k2);
        if (st) {
            ST_A(sb_, mb1, kb, kt1);
            ST_A(sb_, mb1, kb + 1, kt1);
        }
        PH_BAR_LGKM()
        PH_MFMA(0, 2)
        // gate p2/p3 reads of this tile's D23 A-frags (staged at t-1 p3):
        // own newer stages = p0(4) + p1(2) = 6. Last tile: drain.
        if (st) { asm volatile("s_waitcnt vmcnt(6)" ::: "memory"); }
        else    { asm volatile("s_waitcnt vmcnt(0)" ::: "memory"); }
        __builtin_amdgcn_s_barrier();
        __builtin_amdgcn_sched_barrier(0);

        // ---- phase 2: A(wr*4+{2,3}, ks{0,1}); B regs reused; no stages
#pragma unroll
        for (int m2 = 0; m2 < 2; ++m2)
#pragma unroll
            for (int k2 = 0; k2 < 2; ++k2) Af[m2][k2] = RD_A(rb_, wr * 4 + 2 + m2, k2);
        PH_BAR_LGKM()
        PH_MFMA(2, 0)
        __builtin_amdgcn_s_barrier();
        __builtin_amdgcn_sched_barrier(0);

        // ---- phase 3: A(wr*4+{2,3}, ks{2,3}); stage A mb3 pair (D23 of t+1)
#pragma unroll
        for (int m2 = 0; m2 < 2; ++m2)
#pragma unroll
            for (int k2 = 0; k2 < 2; ++k2) Af[m2][k2] = RD_A(rb_, wr * 4 + 2 + m2, 2 + k2);
        if (st) {
            ST_A(sb_, mb3, kb, kt1);
            ST_A(sb_, mb3, kb + 1, kt1);
        }
        PH_BAR_LGKM()
        PH_MFMA(2, 2)
        // tile boundary: tile t+1's D01 frags (staged p0/p1 this tile) must
        // land; own newest 2 (p3's D23 stages) may stay in flight.
        if (st) { asm volatile("s_waitcnt vmcnt(2)" ::: "memory"); }
        __builtin_amdgcn_s_barrier();
        __builtin_amdgcn_sched_barrier(0);
    }

#undef PH_BAR_LGKM
#undef PH_MFMA
#undef ABLK
#undef BBLK
#undef ST_A
#undef ST_B
#undef RD_A
#undef RD_B

    // Epilogue. 32x32 C/D layout (m74/m101): col = lane&31,
    // row = (reg&3) + 8*(reg>>2) + 4*(lane>>5).
    const int rb = khalf << 2;
#pragma unroll
    for (int mi = 0; mi < 4; ++mi) {
#pragma unroll
        for (int ni = 0; ni < 2; ++ni) {
            const int n = bn + wc * 64 + ni * 32 + col;
#pragma unroll
            for (int reg = 0; reg < 16; ++reg) {
                const int m = bm + wr * 128 + mi * 32 + (reg & 3) + 8 * (reg >> 2) + rb;
                C[(size_t)m * N + n] = acc[mi][ni][reg] * wsc + badd[ni];
            }
        }
    }
}

// ---------------------------------------------------------------------------
// 128^2 kernel kept as fallback for shapes not divisible by 256.
// ---------------------------------------------------------------------------
__global__ __launch_bounds__(256) void gemm_bf16_bt(
    const unsigned short* __restrict__ A,
    const unsigned short* __restrict__ B,
    const float* __restrict__ bias,
    const float* __restrict__ wscale_p,
    const float* __restrict__ bscale_p,
    float* __restrict__ C,
    int M, int N, int K) {
    constexpr int BM = 128, BK = 64;
    __shared__ unsigned short ldsA[BM * BK];
    __shared__ unsigned short ldsB[BM * BK];

    const int tid  = threadIdx.x;
    const int wave = tid >> 6;
    const int lane = tid & 63;

    const int bm = blockIdx.y * BM;
    const int bn = blockIdx.x * BM;
    const int wm = (wave >> 1) * 64;
    const int wn = (wave & 1) * 64;

    const float wsc = wscale_p[0];
    const float bsc = bscale_p[0];

    const int col = lane & 31;
    const int khalf = lane >> 5;

    float badd[2];
#pragma unroll
    for (int ni = 0; ni < 2; ++ni)
        badd[ni] = bsc * rintf(bias[bn + wn + ni * 32 + col]);

    const int g_st = ((lane & 7) ^ (lane >> 3)) * 8;
    const unsigned short* gAp[4];
    const unsigned short* gBp[4];
    unsigned short* lA[4];
    unsigned short* lB[4];
#pragma unroll
    for (int i = 0; i < 4; ++i) {
        const int r = wave * 32 + i * 8 + (lane >> 3);
        gAp[i] = A + (size_t)(bm + r) * K + g_st;
        gBp[i] = B + (size_t)(bn + r) * K + g_st;
        lA[i] = &ldsA[(wave * 256 + i * 64) * 8];
        lB[i] = &ldsB[(wave * 256 + i * 64) * 8];
    }

    floatx16 acc[2][2] = {};

    for (int kt = 0; kt < K; kt += BK) {
#pragma unroll
        for (int i = 0; i < 4; ++i) {
            stage16(gAp[i] + kt, lA[i]);
            stage16(gBp[i] + kt, lB[i]);
        }
        __syncthreads();

#pragma unroll
        for (int ks = 0; ks < 4; ++ks) {
            const int gc = ks * 2 + khalf;
            const int slot = (gc ^ (lane & 7)) * 8;
            bf16x8 af[2], bfr[2];
#pragma unroll
            for (int mi = 0; mi < 2; ++mi) {
                const int off = (wm + mi * 32 + col) * BK + slot;
                af[mi] = __builtin_bit_cast(bf16x8, *(const us8*)&ldsA[off]);
            }
#pragma unroll
            for (int ni = 0; ni < 2; ++ni) {
                const int off = (wn + ni * 32 + col) * BK + slot;
                bfr[ni] = __builtin_bit_cast(bf16x8, *(const us8*)&ldsB[off]);
            }
#pragma unroll
            for (int mi = 0; mi < 2; ++mi)
#pragma unroll
                for (int ni = 0; ni < 2; ++ni)
                    acc[mi][ni] = __builtin_amdgcn_mfma_f32_32x32x16_bf16(
                        af[mi], bfr[ni], acc[mi][ni], 0, 0, 0);
        }
        __syncthreads();
    }

    const int rbase = 4 * khalf;
#pragma unroll
    for (int mi = 0; mi < 2; ++mi) {
#pragma unroll
        for (int ni = 0; ni < 2; ++ni) {
            const int n = bn + wn + ni * 32 + col;
#pragma unroll
            for (int reg = 0; reg < 16; ++reg) {
                const int m = bm + wm + mi * 32 + (reg & 3) + 8 * (reg >> 2) + rbase;
                C[(size_t)m * N + n] = acc[mi][ni][reg] * wsc + badd[ni];
            }
        }
    }
}

// ---------------------------------------------------------------------------
// Last-resort fallback (d_ws too small — not expected).
// ---------------------------------------------------------------------------
__global__ __launch_bounds__(256) void fallback_gemm(
    const float* __restrict__ A, const float* __restrict__ W,
    const float* __restrict__ bias, const float* __restrict__ wsp,
    const float* __restrict__ bsp, float* __restrict__ C, int M, int N, int K) {
    const int n = blockIdx.x * 256 + threadIdx.x;
    const int m = blockIdx.y;
    if (n >= N || m >= M) return;
    float s = 0.f;
    for (int k = 0; k < K; ++k)
        s += A[(size_t)m * K + k] * rintf(W[(size_t)n * K + k]);
    C[(size_t)m * N + n] = s * wsp[0] + bsp[0] * rintf(bias[n]);
}

extern "C" void kernel_launch(void* const* d_in, const int* in_sizes, int n_in,
                              void* d_out, int out_size, void* d_ws, size_t ws_size,
                              hipStream_t stream) {
    const float* input  = (const float*)d_in[0];
    const float* weight = (const float*)d_in[1];
    const float* bias   = (const float*)d_in[2];
    const float* wscale = (const float*)d_in[3];
    const float* bscale = (const float*)d_in[4];
    float* out = (float*)d_out;

    const int N = in_sizes[2];
    const int K = in_sizes[1] / N;
    const int M = in_sizes[0] / K;

    const size_t needA = (size_t)M * K * sizeof(unsigned short);
    const size_t needB = (size_t)N * K * sizeof(unsigned short);

    if (ws_size >= needA + needB && (M % 128) == 0 && (N % 128) == 0 &&
        (K % 64) == 0) {
        unsigned short* Abf = (unsigned short*)d_ws;
        unsigned short* Bbf = (unsigned short*)((char*)d_ws + needA);
        const long long nA4 = (long long)M * K / 4;
        const long long nB4 = (long long)N * K / 4;
        const long long nthr = nA4 + nB4;
        cvt_both<<<(unsigned)((nthr + 255) / 256), 256, 0, stream>>>(
            input, Abf, nA4, weight, Bbf, nB4);

        const int nwg256 = (M / 256) * (N / 256);
        if ((M % 256) == 0 && (N % 256) == 0 && (K / 64) >= 1 &&
            (nwg256 % 8) == 0) {
            gemm256_fm<<<dim3(nwg256), 512, 0, stream>>>(
                Abf, Bbf, bias, wscale, bscale, out, M, N, K);
        } else {
            dim3 grid(N / 128, M / 128);
            gemm_bf16_bt<<<grid, 256, 0, stream>>>(Abf, Bbf, bias, wscale,
                                                   bscale, out, M, N, K);
        }
    } else {
        dim3 grid((N + 255) / 256, M);
        fallback_gemm<<<grid, 256, 0, stream>>>(input, weight, bias, wscale, bscale, out, M, N, K);
    }
}

// Round 5
// 541.573 us; speedup vs baseline: 1.1646x; 1.1646x over previous
//
#include <hip/hip_runtime.h>
#include <stdint.h>

// ---------------------------------------------------------------------------
// out[n_tok, out_f] = input @ (w_scale * round(weight))^T + b_scale*round(bias)
// M=8192, N=4096, K=4096, fp32 in/out.
//
// R8b: resubmit of R8 (round 4 was an infra failure: "MI355X container
// failed twice" — no pytest verdict, no counters; kernel re-audited for
// barrier divergence / vmcnt ledger / OOB — all clean).
//
// R8 theory: synthesis of the R6/R7 experiment matrix.
//   R4-R6: coalesced staging + 4-way-conflicted LDS reads -> 314us, Mfma 38.
//   R7:    scattered staging + conflict-free LDS reads    -> 395us, Mfma 28.5
//          (conflicts->0 confirmed the layout theory, but per-lane global
//          addresses turned each gload_lds into 64x16B scattered requests).
// Fix: FRAGMENT-MAJOR GLOBAL layout. cvt writes A',B' as
// [R/32][K/16][64][8] bf16 (= the exact MFMA operand order). Then:
//   - gload_lds per fragment = frag_base + lane*16: ONE contiguous 1KiB
//     span per wave instruction (better than R6's 8x128B);
//   - LDS = linear fragment blocks, reads = uniform + lane*16: conflict-free
//     (bit-identical LDS contents to R7, which passed);
//   - near-zero VALU address math in the GEMM.
// cvt_frag: reads 64B-per-row strided (full lines, TLP-hidden), writes one
// contiguous 1KiB fragment per wave (ideal store coalescing).
// Race fix vs R6/R7: p1 reads frags staged at t-1 p3; gate moved to END-p0
// (vmcnt(4), last tile vmcnt(0)) so they are forced BEFORE p1's reads.
// Schedule/barriers/MFMA order/epilogue: identical to R7 (single-variable).
// ---------------------------------------------------------------------------

using bf16x8   = __attribute__((ext_vector_type(8))) __bf16;
using floatx16 = __attribute__((ext_vector_type(16))) float;
using us8      = __attribute__((ext_vector_type(8))) unsigned short;
using us4      = __attribute__((ext_vector_type(4))) unsigned short;

__device__ __forceinline__ unsigned short f2bf_rne(float x) {
    unsigned int u = __float_as_uint(x);
    return (unsigned short)((u + 0x7fffu + ((u >> 16) & 1u)) >> 16);
}

__device__ __forceinline__ void stage16(const unsigned short* g, unsigned short* l) {
    __builtin_amdgcn_global_load_lds(
        (__attribute__((address_space(1))) void*)g,
        (__attribute__((address_space(3))) void*)l,
        16, 0, 0);
}

// ---------------------------------------------------------------------------
// Fragment-major conversion. in: fp32 [R][K] row-major. out: bf16
// [R/32][K/16][64][8]; lane = khalf*32 + r5 holds
// in[rg*32 + r5][ksg*16 + khalf*8 + j], j=0..7.
// Thread map: lane r5 -> row (strided 64B-per-row reads, full lines);
// one wave writes one contiguous 1KiB fragment per iteration.
// Launch: grid(R/32, 4), block 256. Requires K % 256 == 0.
// ---------------------------------------------------------------------------
template<bool DO_RINT>
__global__ __launch_bounds__(256) void cvt_frag(
    const float* __restrict__ in, unsigned short* __restrict__ out, int K) {
    const int KS16 = K >> 4;
    const int rg   = blockIdx.x;
    const int w    = threadIdx.x >> 6;
    const int lane = threadIdx.x & 63;
    const int r5   = lane & 31;
    const int kh   = lane >> 5;
    const int QF   = KS16 >> 2;                 // frags per y-block
    const int bks  = blockIdx.y * QF;

    const float* src = in + (size_t)(rg * 32 + r5) * K + kh * 8;
    unsigned short* dst = out + ((size_t)(rg * KS16) << 9) + (lane << 3);

    for (int i = w; i < QF; i += 4) {
        const int ksg = bks + i;
        const float* s = src + ksg * 16;
        float4 v0 = *(const float4*)(s);
        float4 v1 = *(const float4*)(s + 4);
        us8 o;
        if (DO_RINT) {
            o = us8{ f2bf_rne(rintf(v0.x)), f2bf_rne(rintf(v0.y)),
                     f2bf_rne(rintf(v0.z)), f2bf_rne(rintf(v0.w)),
                     f2bf_rne(rintf(v1.x)), f2bf_rne(rintf(v1.y)),
                     f2bf_rne(rintf(v1.z)), f2bf_rne(rintf(v1.w)) };
        } else {
            o = us8{ f2bf_rne(v0.x), f2bf_rne(v0.y),
                     f2bf_rne(v0.z), f2bf_rne(v0.w),
                     f2bf_rne(v1.x), f2bf_rne(v1.y),
                     f2bf_rne(v1.z), f2bf_rne(v1.w) };
        }
        *(us8*)(dst + ((size_t)ksg << 9)) = o;
    }
}

// ---------------------------------------------------------------------------
// Legacy row-major conversion (fallback path only).
// ---------------------------------------------------------------------------
__global__ __launch_bounds__(256) void cvt_both(
    const float* __restrict__ inA, unsigned short* __restrict__ outA, long long nA4,
    const float* __restrict__ inB, unsigned short* __restrict__ outB, long long nB4) {
    const long long i = (long long)blockIdx.x * 256 + threadIdx.x;
    if (i < nA4) {
        float4 v = ((const float4*)inA)[i];
        us4 o = { f2bf_rne(v.x), f2bf_rne(v.y), f2bf_rne(v.z), f2bf_rne(v.w) };
        ((us4*)outA)[i] = o;
    } else {
        const long long j = i - nA4;
        if (j < nB4) {
            float4 v = ((const float4*)inB)[j];
            us4 o = { f2bf_rne(rintf(v.x)), f2bf_rne(rintf(v.y)),
                      f2bf_rne(rintf(v.z)), f2bf_rne(rintf(v.w)) };
            ((us4*)outB)[j] = o;
        }
    }
}

// ---------------------------------------------------------------------------
// 256x256 phase-paired bf16 GEMM, fragment-major global operands.
// Block=512 (8 waves, 2Mx4N). Wave -> 128x64 output; 4x2 grid of 32x32x16
// MFMA accumulators. LDS: 32 frag-blocks x 1024B per matrix per buffer.
// ---------------------------------------------------------------------------
__global__ __launch_bounds__(512) void gemm256_fg(
    const unsigned short* __restrict__ A,   // [M/32][K/16][64][8] bf16
    const unsigned short* __restrict__ B,   // [N/32][K/16][64][8] bf16
    const float* __restrict__ bias,
    const float* __restrict__ wscale_p,
    const float* __restrict__ bscale_p,
    float* __restrict__ C,                  // [M][N] fp32
    int M, int N, int K) {
    constexpr int TILE = 16384;                 // shorts per matrix per buffer
    __shared__ unsigned short ldsA[2 * TILE];   // 64 KiB
    __shared__ unsigned short ldsB[2 * TILE];   // 64 KiB

    const int tid  = threadIdx.x;
    const int wave = tid >> 6;
    const int lane = tid & 63;

    // bijective XCD swizzle (host guarantees gridDim.x % 8 == 0)
    const int nbx = N >> 8;
    int wg;
    {
        const int cpx = (int)gridDim.x >> 3;
        wg = ((int)blockIdx.x & 7) * cpx + ((int)blockIdx.x >> 3);
    }
    const int bm = (wg / nbx) << 8;
    const int bn = (wg % nbx) << 8;

    const int wr    = wave >> 2;          // 0/1   -> A rows wr*128
    const int wc    = wave & 3;           // 0..3  -> B rows wc*64
    const int col   = lane & 31;
    const int khalf = lane >> 5;

    const int KS16 = K >> 4;
    const int bmb  = bm >> 5;             // global A frag-row base
    const int bnb  = bn >> 5;             // global B frag-row base

    // per-lane global base (lane*16B inside each 1KiB fragment)
    const unsigned short* gAf = A + (lane << 3);
    const unsigned short* gBf = B + (lane << 3);

    const int lane16 = lane << 3;         // shorts

    const float wsc = wscale_p[0];
    const float bsc = bscale_p[0];
    float badd[2];
#pragma unroll
    for (int ni = 0; ni < 2; ++ni)
        badd[ni] = bsc * rintf(bias[bn + wc * 64 + ni * 32 + col]);

    const int NT = K >> 6;

#define ABLK(buf, mb, ks) ((buf) * TILE + (((mb) * 4 + (ks)) << 9))
#define BBLK(buf, nb, ks) ((buf) * TILE + (((nb) * 4 + (ks)) << 9))
// kf = frag-column index (t*4 + ks)
#define ST_A(buf, mb, ks, kf) \
    stage16(gAf + (((size_t)(bmb + (mb)) * KS16 + (kf)) << 9), &ldsA[ABLK(buf, mb, ks)])
#define ST_B(buf, nb, ks, kf) \
    stage16(gBf + (((size_t)(bnb + (nb)) * KS16 + (kf)) << 9), &ldsB[BBLK(buf, nb, ks)])
#define RD_A(buf, mb, ks) \
    __builtin_bit_cast(bf16x8, *(const us8*)&ldsA[ABLK(buf, mb, ks) + lane16])
#define RD_B(buf, nb, ks) \
    __builtin_bit_cast(bf16x8, *(const us8*)&ldsB[BBLK(buf, nb, ks) + lane16])

    // ---- prologue: stage tile 0 -> buf0. Order: B x4, A ks0..3.
#pragma unroll
    for (int i = 0; i < 4; ++i) ST_B(0, wave, i, i);
    ST_A(0, wave, 0, 0);
    ST_A(0, wave, 1, 1);
    ST_A(0, wave, 2, 2);
    ST_A(0, wave, 3, 3);
    asm volatile("s_waitcnt vmcnt(2)" ::: "memory");   // B x4 + A ks01 landed
    __builtin_amdgcn_s_barrier();
    __builtin_amdgcn_sched_barrier(0);

    floatx16 acc[4][2] = {};

#define PH_BAR_LGKM()                                        \
    __builtin_amdgcn_s_barrier();                            \
    asm volatile("s_waitcnt lgkmcnt(0)" ::: "memory");       \
    __builtin_amdgcn_sched_barrier(0);

#define PH_MFMA(MIB, KSB)                                                     \
    __builtin_amdgcn_s_setprio(1);                                            \
    _Pragma("unroll") for (int k2 = 0; k2 < 2; ++k2)                          \
        _Pragma("unroll") for (int m2 = 0; m2 < 2; ++m2)                      \
            _Pragma("unroll") for (int ni = 0; ni < 2; ++ni)                  \
                acc[(MIB) + m2][ni] = __builtin_amdgcn_mfma_f32_32x32x16_bf16(\
                    Af[m2][k2], Bf[ni][(KSB) + k2], acc[(MIB) + m2][ni],      \
                    0, 0, 0);                                                 \
    __builtin_amdgcn_s_setprio(0);                                            \
    __builtin_amdgcn_sched_barrier(0);

    for (int t = 0; t < NT; ++t) {
        const int rb_ = t & 1;
        const int sb_ = (t + 1) & 1;
        const int kf1 = (t + 1) << 2;              // frag-column base of t+1
        const bool st = (t + 1 < NT);

        bf16x8 Af[2][2];
        bf16x8 Bf[2][4];

        // ---- phase 0: read A(wr4+{0,1}, ks{0,1}) + B(wc2+{0,1}, ks{0,1});
        //      stage 4 B-frags of t+1
#pragma unroll
        for (int m2 = 0; m2 < 2; ++m2)
#pragma unroll
            for (int k2 = 0; k2 < 2; ++k2) Af[m2][k2] = RD_A(rb_, wr * 4 + m2, k2);
#pragma unroll
        for (int ni = 0; ni < 2; ++ni)
#pragma unroll
            for (int k2 = 0; k2 < 2; ++k2) Bf[ni][k2] = RD_B(rb_, wc * 2 + ni, k2);
        if (st) {
#pragma unroll
            for (int i = 0; i < 4; ++i) ST_B(sb_, wave, i, kf1 + i);
        }
        PH_BAR_LGKM()
        PH_MFMA(0, 0)
        // force t-1 p3's A(ks23) stages (read next phase). Own p0 stages = 4.
        if (st) { asm volatile("s_waitcnt vmcnt(4)" ::: "memory"); }
        else    { asm volatile("s_waitcnt vmcnt(0)" ::: "memory"); }
        __builtin_amdgcn_s_barrier();
        __builtin_amdgcn_sched_barrier(0);

        // ---- phase 1: read ks{2,3} (A + B); stage A ks0, ks1 of t+1
#pragma unroll
        for (int m2 = 0; m2 < 2; ++m2)
#pragma unroll
            for (int k2 = 0; k2 < 2; ++k2) Af[m2][k2] = RD_A(rb_, wr * 4 + m2, 2 + k2);
#pragma unroll
        for (int ni = 0; ni < 2; ++ni)
#pragma unroll
            for (int k2 = 0; k2 < 2; ++k2) Bf[ni][2 + k2] = RD_B(rb_, wc * 2 + ni, 2 + k2);
        if (st) {
            ST_A(sb_, wave, 0, kf1);
            ST_A(sb_, wave, 1, kf1 + 1);
        }
        PH_BAR_LGKM()
        PH_MFMA(0, 2)
        __builtin_amdgcn_s_barrier();
        __builtin_amdgcn_sched_barrier(0);

        // ---- phase 2: read A(wr4+{2,3}, ks{0,1}); B regs reused; no stages
#pragma unroll
        for (int m2 = 0; m2 < 2; ++m2)
#pragma unroll
            for (int k2 = 0; k2 < 2; ++k2) Af[m2][k2] = RD_A(rb_, wr * 4 + 2 + m2, k2);
        PH_BAR_LGKM()
        PH_MFMA(2, 0)
        __builtin_amdgcn_s_barrier();
        __builtin_amdgcn_sched_barrier(0);

        // ---- phase 3: read A(wr4+{2,3}, ks{2,3}); stage A ks2, ks3 of t+1
#pragma unroll
        for (int m2 = 0; m2 < 2; ++m2)
#pragma unroll
            for (int k2 = 0; k2 < 2; ++k2) Af[m2][k2] = RD_A(rb_, wr * 4 + 2 + m2, 2 + k2);
        if (st) {
            ST_A(sb_, wave, 2, kf1 + 2);
            ST_A(sb_, wave, 3, kf1 + 3);
        }
        PH_BAR_LGKM()
        PH_MFMA(2, 2)
        // tile boundary: t+1's B x4 + A ks01 (first 6 of own 8) must land;
        // own newest 2 (A ks23) may stay in flight.
        if (st) { asm volatile("s_waitcnt vmcnt(2)" ::: "memory"); }
        __builtin_amdgcn_s_barrier();
        __builtin_amdgcn_sched_barrier(0);
    }

#undef PH_BAR_LGKM
#undef PH_MFMA
#undef ABLK
#undef BBLK
#undef ST_A
#undef ST_B
#undef RD_A
#undef RD_B

    // Epilogue. 32x32 C/D layout (m74/m101): col = lane&31,
    // row = (reg&3) + 8*(reg>>2) + 4*(lane>>5).
    const int rb = khalf << 2;
#pragma unroll
    for (int mi = 0; mi < 4; ++mi) {
#pragma unroll
        for (int ni = 0; ni < 2; ++ni) {
            const int n = bn + wc * 64 + ni * 32 + col;
#pragma unroll
            for (int reg = 0; reg < 16; ++reg) {
                const int m = bm + wr * 128 + mi * 32 + (reg & 3) + 8 * (reg >> 2) + rb;
                C[(size_t)m * N + n] = acc[mi][ni][reg] * wsc + badd[ni];
            }
        }
    }
}

// ---------------------------------------------------------------------------
// 128^2 kernel kept as fallback for shapes not divisible by 256 (row-major).
// ---------------------------------------------------------------------------
__global__ __launch_bounds__(256) void gemm_bf16_bt(
    const unsigned short* __restrict__ A,
    const unsigned short* __restrict__ B,
    const float* __restrict__ bias,
    const float* __restrict__ wscale_p,
    const float* __restrict__ bscale_p,
    float* __restrict__ C,
    int M, int N, int K) {
    constexpr int BM = 128, BK = 64;
    __shared__ unsigned short ldsA[BM * BK];
    __shared__ unsigned short ldsB[BM * BK];

    const int tid  = threadIdx.x;
    const int wave = tid >> 6;
    const int lane = tid & 63;

    const int bm = blockIdx.y * BM;
    const int bn = blockIdx.x * BM;
    const int wm = (wave >> 1) * 64;
    const int wn = (wave & 1) * 64;

    const float wsc = wscale_p[0];
    const float bsc = bscale_p[0];

    const int col = lane & 31;
    const int khalf = lane >> 5;

    float badd[2];
#pragma unroll
    for (int ni = 0; ni < 2; ++ni)
        badd[ni] = bsc * rintf(bias[bn + wn + ni * 32 + col]);

    const int g_st = ((lane & 7) ^ (lane >> 3)) * 8;
    const unsigned short* gAp[4];
    const unsigned short* gBp[4];
    unsigned short* lA[4];
    unsigned short* lB[4];
#pragma unroll
    for (int i = 0; i < 4; ++i) {
        const int r = wave * 32 + i * 8 + (lane >> 3);
        gAp[i] = A + (size_t)(bm + r) * K + g_st;
        gBp[i] = B + (size_t)(bn + r) * K + g_st;
        lA[i] = &ldsA[(wave * 256 + i * 64) * 8];
        lB[i] = &ldsB[(wave * 256 + i * 64) * 8];
    }

    floatx16 acc[2][2] = {};

    for (int kt = 0; kt < K; kt += BK) {
#pragma unroll
        for (int i = 0; i < 4; ++i) {
            stage16(gAp[i] + kt, lA[i]);
            stage16(gBp[i] + kt, lB[i]);
        }
        __syncthreads();

#pragma unroll
        for (int ks = 0; ks < 4; ++ks) {
            const int gc = ks * 2 + khalf;
            const int slot = (gc ^ (lane & 7)) * 8;
            bf16x8 af[2], bfr[2];
#pragma unroll
            for (int mi = 0; mi < 2; ++mi) {
                const int off = (wm + mi * 32 + col) * BK + slot;
                af[mi] = __builtin_bit_cast(bf16x8, *(const us8*)&ldsA[off]);
            }
#pragma unroll
            for (int ni = 0; ni < 2; ++ni) {
                const int off = (wn + ni * 32 + col) * BK + slot;
                bfr[ni] = __builtin_bit_cast(bf16x8, *(const us8*)&ldsB[off]);
            }
#pragma unroll
            for (int mi = 0; mi < 2; ++mi)
#pragma unroll
                for (int ni = 0; ni < 2; ++ni)
                    acc[mi][ni] = __builtin_amdgcn_mfma_f32_32x32x16_bf16(
                        af[mi], bfr[ni], acc[mi][ni], 0, 0, 0);
        }
        __syncthreads();
    }

    const int rbase = 4 * khalf;
#pragma unroll
    for (int mi = 0; mi < 2; ++mi) {
#pragma unroll
        for (int ni = 0; ni < 2; ++ni) {
            const int n = bn + wn + ni * 32 + col;
#pragma unroll
            for (int reg = 0; reg < 16; ++reg) {
                const int m = bm + wm + mi * 32 + (reg & 3) + 8 * (reg >> 2) + rbase;
                C[(size_t)m * N + n] = acc[mi][ni][reg] * wsc + badd[ni];
            }
        }
    }
}

// ---------------------------------------------------------------------------
// Last-resort fallback (d_ws too small — not expected).
// ---------------------------------------------------------------------------
__global__ __launch_bounds__(256) void fallback_gemm(
    const float* __restrict__ A, const float* __restrict__ W,
    const float* __restrict__ bias, const float* __restrict__ wsp,
    const float* __restrict__ bsp, float* __restrict__ C, int M, int N, int K) {
    const int n = blockIdx.x * 256 + threadIdx.x;
    const int m = blockIdx.y;
    if (n >= N || m >= M) return;
    float s = 0.f;
    for (int k = 0; k < K; ++k)
        s += A[(size_t)m * K + k] * rintf(W[(size_t)n * K + k]);
    C[(size_t)m * N + n] = s * wsp[0] + bsp[0] * rintf(bias[n]);
}

extern "C" void kernel_launch(void* const* d_in, const int* in_sizes, int n_in,
                              void* d_out, int out_size, void* d_ws, size_t ws_size,
                              hipStream_t stream) {
    const float* input  = (const float*)d_in[0];
    const float* weight = (const float*)d_in[1];
    const float* bias   = (const float*)d_in[2];
    const float* wscale = (const float*)d_in[3];
    const float* bscale = (const float*)d_in[4];
    float* out = (float*)d_out;

    const int N = in_sizes[2];
    const int K = in_sizes[1] / N;
    const int M = in_sizes[0] / K;

    const size_t needA = (size_t)M * K * sizeof(unsigned short);
    const size_t needB = (size_t)N * K * sizeof(unsigned short);
    const bool big = ws_size >= needA + needB;

    const int nwg256 = (M / 256) * (N / 256);

    if (big && (M % 256) == 0 && (N % 256) == 0 && (K % 256) == 0 &&
        (nwg256 % 8) == 0) {
        unsigned short* Abf = (unsigned short*)d_ws;
        unsigned short* Bbf = (unsigned short*)((char*)d_ws + needA);
        cvt_frag<false><<<dim3(M / 32, 4), 256, 0, stream>>>(input, Abf, K);
        cvt_frag<true><<<dim3(N / 32, 4), 256, 0, stream>>>(weight, Bbf, K);
        gemm256_fg<<<dim3(nwg256), 512, 0, stream>>>(
            Abf, Bbf, bias, wscale, bscale, out, M, N, K);
    } else if (big && (M % 128) == 0 && (N % 128) == 0 && (K % 64) == 0) {
        unsigned short* Abf = (unsigned short*)d_ws;
        unsigned short* Bbf = (unsigned short*)((char*)d_ws + needA);
        const long long nA4 = (long long)M * K / 4;
        const long long nB4 = (long long)N * K / 4;
        const long long nthr = nA4 + nB4;
        cvt_both<<<(unsigned)((nthr + 255) / 256), 256, 0, stream>>>(
            input, Abf, nA4, weight, Bbf, nB4);
        dim3 grid(N / 128, M / 128);
        gemm_bf16_bt<<<grid, 256, 0, stream>>>(Abf, Bbf, bias, wscale,
                                               bscale, out, M, N, K);
    } else {
        dim3 grid((N + 255) / 256, M);
        fallback_gemm<<<grid, 256, 0, stream>>>(input, weight, bias, wscale, bscale, out, M, N, K);
    }
}